// Round 4
// baseline (650.323 us; speedup 1.0000x reference)
//
#include <hip/hip_runtime.h>

// Problem constants
#define C_DIM 512
#define V_DIM 1024

typedef __attribute__((ext_vector_type(8))) short short8;    // 8 bf16 (4 VGPRs)
typedef __attribute__((ext_vector_type(4))) float f32x4;
typedef __attribute__((ext_vector_type(16))) float f32x16;   // 32x32 MFMA acc

__device__ __forceinline__ short f2bf(float f) {
  unsigned int u = __float_as_uint(f);
  u += 0x7fffu + ((u >> 16) & 1u);           // RNE
  return (short)(u >> 16);
}

__device__ __forceinline__ float fast_tanh_f(float x) {
  // tanh(x) = 1 - 2/(exp(2x)+1); saturates correctly at +/-inf
  float e = __expf(2.0f * x);
  return fmaf(-2.0f, __builtin_amdgcn_rcpf(e + 1.0f), 1.0f);
}

// ---------------------------------------------------------------------------
// Kernel 1 (unchanged, harness-verified): cast W (V,C) fp32 -> bf16 into the
// 32x32-MFMA B-fragment image:
//   chunk (vt,kc) = 16 KB; inside: [wn(4)][nt(2)][s(2)][hi(2)][c32(32)] x 16B
//   element (v,c): v = vt*256 + wn*64 + nt*32 + c32
//                  c = kc*32 + s*16 + hi*8 + j   (j = 0..7 inside the 16B)
// ---------------------------------------------------------------------------
__global__ __launch_bounds__(256) void wswz_kernel(const float* __restrict__ W,
                                                   char* __restrict__ wsw) {
  const int i = blockIdx.x * 256 + threadIdx.x;   // 65536 threads
  const int v = i >> 6;
  const int c0 = (i & 63) << 3;
  const float* wp = W + (size_t)v * C_DIM + c0;
  const f32x4 w0 = *(const f32x4*)(wp);
  const f32x4 w1 = *(const f32x4*)(wp + 4);
  short8 pk;
  pk[0] = f2bf(w0[0]); pk[1] = f2bf(w0[1]); pk[2] = f2bf(w0[2]); pk[3] = f2bf(w0[3]);
  pk[4] = f2bf(w1[0]); pk[5] = f2bf(w1[1]); pk[6] = f2bf(w1[2]); pk[7] = f2bf(w1[3]);
  const int vt = v >> 8, vloc = v & 255;
  const int wn = vloc >> 6, nt = (vloc >> 5) & 1, c32 = vloc & 31;
  const int kc = c0 >> 5, s = (c0 >> 4) & 1, hi = (c0 >> 3) & 1;
  char* dst = wsw + (size_t)(vt * 16 + kc) * 16384 +
              wn * 4096 + nt * 2048 + s * 1024 + hi * 512 + c32 * 16;
  *(short8*)dst = pk;
}

// ---------------------------------------------------------------------------
// Kernel 2: persistent-A joiner, HIGH-TLP variant.
//   Identical verified skeleton/mappings as before (2048 blocks, 64-row
//   panels, 64 KB A image, barrier-free loop, B global->reg ping-pong,
//   nontemporal epilogue), but re-partitioned as:
//     512 threads = 8 waves (wm 2 x wn 4), wave tile 32x64, acc = 2x f32x16.
//   Same 64 KB LDS -> still 2 blocks/CU, but 16 waves/CU = 4 waves/SIMD:
//   doubles the latency-hiding TLP that R3's 2 waves/SIMD lacked.
//   VGPR ~110 (acc 32 + bfr 32 + A 8 + addr) -> no pressure at 4 waves/SIMD.
// ---------------------------------------------------------------------------
__global__ __launch_bounds__(512, 4) void joiner_kernel(
    const float* __restrict__ enc, const float* __restrict__ pred,
    const char* __restrict__ wsw, const float* __restrict__ bias,
    float* __restrict__ out) {
  extern __shared__ char smem[];          // 65536 B A image
  const int tid = threadIdx.x;
  const int lane = tid & 63;
  const int wv = tid >> 6;                // wave 0..7
  const int wm = wv >> 2;                 // row half (32 rows)
  const int wn = wv & 3;                  // 64-col block
  const int l31 = lane & 31, hf = lane >> 5;

  // Bijective XCD swizzle (2048 % 8 == 0): 256 consecutive panels per XCD.
  const int bid = blockIdx.x;
  const int rp = ((bid & 7) << 8) | (bid >> 3);   // row panel 0..2047
  const int n = rp >> 8;                  // batch (rp = n*256 + t)

  // ---- Phase 1: stage A = tanh(enc+pred), 64 rows x 512 k, bf16 (64 KB)
  // Image: [kc(16)][f(4)=mt*2+s][hf(2)][l31(32)] x 16 B.
  // 512 threads stage 8 KB (2 kc) per pass, 8 passes; one barrier total.
  {
    const int rem = tid & 255;
    const int f = rem >> 6, hf5 = (rem >> 5) & 1, l = rem & 31;
    const int u = (f >> 1) * 32 + l;              // row
    const int k0 = (tid >> 8) * 32 + (f & 1) * 16 + hf5 * 8;
    const float* pe = enc + (size_t)rp * C_DIM + k0;
    const float* pp = pred + ((size_t)(n * 64 + u)) * C_DIM + k0;
    char* adst = smem + tid * 16;                 // linear ds_write_b128
#pragma unroll 2
    for (int p = 0; p < 8; ++p) {                 // kc = p*2 + (tid>>8)
      const f32x4 e0 = *(const f32x4*)(pe + p * 64);
      const f32x4 e1 = *(const f32x4*)(pe + p * 64 + 4);
      const f32x4 p0 = *(const f32x4*)(pp + p * 64);
      const f32x4 p1 = *(const f32x4*)(pp + p * 64 + 4);
      short8 pk;
      pk[0] = f2bf(fast_tanh_f(e0[0] + p0[0]));
      pk[1] = f2bf(fast_tanh_f(e0[1] + p0[1]));
      pk[2] = f2bf(fast_tanh_f(e0[2] + p0[2]));
      pk[3] = f2bf(fast_tanh_f(e0[3] + p0[3]));
      pk[4] = f2bf(fast_tanh_f(e1[0] + p1[0]));
      pk[5] = f2bf(fast_tanh_f(e1[1] + p1[1]));
      pk[6] = f2bf(fast_tanh_f(e1[2] + p1[2]));
      pk[7] = f2bf(fast_tanh_f(e1[3] + p1[7 - 7]));   // p1[0]
      pk[7] = f2bf(fast_tanh_f(e1[3] + p1[3]));
      *(short8*)(adst + p * 8192) = pk;
    }
  }
  __syncthreads();                        // the ONLY barrier

  // ---- fragment bases
  // A frag (kc,s): smem + kc*4096 + (wm*2+s)*1024 + hf*512 + l31*16
  const char* ab = smem + wm * 2048 + hf * 512 + l31 * 16;
  // B frag (g,nt,s): wsw + g*16384 + wn*4096 + (nt*2+s)*1024 + hf*512 + l31*16
  const char* wb = wsw + wn * 4096 + hf * 512 + l31 * 16;

  f32x16 acc[2];                          // nt = 0,1
#pragma unroll
  for (int nt = 0; nt < 2; ++nt)
#pragma unroll
    for (int r = 0; r < 16; ++r) acc[nt][r] = 0.0f;

  short8 bfr[2][4];                       // B ping-pong, frag id = nt*2+s

  // ---- prologue: B fragments for g = 0 (vt=0, kc=0)
#pragma unroll
  for (int f = 0; f < 4; ++f) bfr[0][f] = *(const short8*)(wb + f * 1024);

#pragma unroll 1
  for (int vt = 0; vt < 4; ++vt) {
    const char* wg = wb + (size_t)vt * 262144;    // this v-tile's 16 chunks
#pragma unroll
    for (int kc = 0; kc < 16; ++kc) {
      const int cb = kc & 1, nb = cb ^ 1;         // static after full unroll

      // B prefetch for g+1, issued first (longest time in flight)
      if (kc < 15 || vt < 3) {
        const char* bp = wg + (kc + 1) * 16384;
#pragma unroll
        for (int f = 0; f < 4; ++f)
          bfr[nb][f] = *(const short8*)(bp + f * 1024);
      }

      // A fragments just-in-time from static LDS image
      const char* ap = ab + kc * 4096;
      const short8 a_s0 = *(const short8*)(ap);
      const short8 a_s1 = *(const short8*)(ap + 1024);

      __builtin_amdgcn_s_setprio(1);
      acc[0] = __builtin_amdgcn_mfma_f32_32x32x16_bf16(a_s0, bfr[cb][0], acc[0], 0, 0, 0);
      acc[1] = __builtin_amdgcn_mfma_f32_32x32x16_bf16(a_s0, bfr[cb][2], acc[1], 0, 0, 0);
      acc[0] = __builtin_amdgcn_mfma_f32_32x32x16_bf16(a_s1, bfr[cb][1], acc[0], 0, 0, 0);
      acc[1] = __builtin_amdgcn_mfma_f32_32x32x16_bf16(a_s1, bfr[cb][3], acc[1], 0, 0, 0);
      __builtin_amdgcn_s_setprio(0);
    }

    // ---- epilogue for this v-tile (no barrier; overlaps resident waves)
    // C/D layout (m74/m101): col = lane&31, row = (r&3) + 8*(r>>2) + 4*hf
    {
      const int colb = (vt << 8) + (wn << 6) + l31;
      float* ob = out + ((size_t)rp * 64 + wm * 32 + hf * 4) * V_DIM + colb;
#pragma unroll
      for (int nt = 0; nt < 2; ++nt) {
        const float bb = bias[colb + nt * 32];
#pragma unroll
        for (int r = 0; r < 16; ++r) {
          const int row_off = (r & 3) + 8 * (r >> 2);
          __builtin_nontemporal_store(acc[nt][r] + bb,
                                      ob + (size_t)row_off * V_DIM + nt * 32);
          acc[nt][r] = 0.0f;              // reset for next v-tile
        }
      }
    }
  }
}

extern "C" void kernel_launch(void* const* d_in, const int* in_sizes, int n_in,
                              void* d_out, int out_size, void* d_ws, size_t ws_size,
                              hipStream_t stream) {
  const float* enc  = (const float*)d_in[0];   // (8,256,512)
  const float* pred = (const float*)d_in[1];   // (8,64,512)
  const float* W    = (const float*)d_in[2];   // (1024,512)
  const float* bias = (const float*)d_in[3];   // (1024,)
  float* out = (float*)d_out;                  // (8,256,64,1024)
  char* wsw = (char*)d_ws;                     // 1 MB swizzled bf16 W

  wswz_kernel<<<dim3(256), dim3(256), 0, stream>>>(W, wsw);

  (void)hipFuncSetAttribute((const void*)joiner_kernel,
                            hipFuncAttributeMaxDynamicSharedMemorySize, 65536);
  joiner_kernel<<<dim3(2048), dim3(512), 65536, stream>>>(enc, pred, wsw, bias, out);
}